// Round 1
// baseline (446.766 us; speedup 1.0000x reference)
//
#include <hip/hip_runtime.h>
#include <hip/hip_bf16.h>
#include <cstdint>

#define C_DIM 256
#define NH 8
#define HD 32
#define QKV_N 768
#define KT 32

// ---------------------------------------------------------------------------
// Tiled fp32 GEMM: out[M,N] = A[M,256] @ W[256,N] + bias[N], with optional
// scale applied to columns < scale_cols (used to fold the q * hd^-0.5 scale).
// Block: 256 threads (16x16), tile 64x64, BK=16, 4x4 register micro-tile.
// ---------------------------------------------------------------------------
__global__ __launch_bounds__(256) void gemm_bias_kernel(
    const float* __restrict__ A, const float* __restrict__ W,
    const float* __restrict__ bias, float* __restrict__ out,
    int M, int N, float scale, int scale_cols)
{
  __shared__ float As[16][72];  // [k][m], stride 72 floats = 288B (16B aligned, 2-way banks)
  __shared__ float Bs[16][64];  // [k][n]
  const int K = 256;

  const int tid = threadIdx.x;
  const int tx = tid & 15, ty = tid >> 4;
  const int m0 = blockIdx.x * 64;
  const int n0 = blockIdx.y * 64;

  float acc[4][4];
#pragma unroll
  for (int i = 0; i < 4; ++i)
#pragma unroll
    for (int j = 0; j < 4; ++j) acc[i][j] = 0.f;

  const int lrow = tid >> 2;        // 0..63  (A tile row)
  const int lc4  = (tid & 3) * 4;   // 0,4,8,12 (A tile col)
  const int brow = tid >> 4;        // 0..15  (B tile row)
  const int bc4  = (tid & 15) * 4;  // 0..60  (B tile col)

  for (int k0 = 0; k0 < K; k0 += 16) {
    float4 av = make_float4(0.f, 0.f, 0.f, 0.f);
    const int gr = m0 + lrow;
    if (gr < M) av = *(const float4*)(A + (size_t)gr * K + k0 + lc4);
    const float4 bv = *(const float4*)(W + (size_t)(k0 + brow) * N + n0 + bc4);

    __syncthreads();  // protect previous iteration's LDS reads
    As[lc4 + 0][lrow] = av.x;
    As[lc4 + 1][lrow] = av.y;
    As[lc4 + 2][lrow] = av.z;
    As[lc4 + 3][lrow] = av.w;
    *(float4*)&Bs[brow][bc4] = bv;
    __syncthreads();

#pragma unroll
    for (int kk = 0; kk < 16; ++kk) {
      float a[4], b[4];
      *(float4*)a = *(const float4*)&As[kk][ty * 4];
      *(float4*)b = *(const float4*)&Bs[kk][tx * 4];
#pragma unroll
      for (int i = 0; i < 4; ++i)
#pragma unroll
        for (int j = 0; j < 4; ++j)
          acc[i][j] = fmaf(a[i], b[j], acc[i][j]);
    }
  }

  const int col = n0 + tx * 4;
  const float4 bb = *(const float4*)(bias + col);
  const float sc = (col < scale_cols) ? scale : 1.f;
#pragma unroll
  for (int i = 0; i < 4; ++i) {
    const int r = m0 + ty * 4 + i;
    if (r < M) {
      float4 o;
      o.x = (acc[i][0] + bb.x) * sc;
      o.y = (acc[i][1] + bb.y) * sc;
      o.z = (acc[i][2] + bb.z) * sc;
      o.w = (acc[i][3] + bb.w) * sc;
      *(float4*)(out + (size_t)r * N + col) = o;
    }
  }
}

// ---------------------------------------------------------------------------
// Ragged attention, one thread per query row, online softmax over key tiles.
// qkv layout per token row (768 floats): [q(h*32+d) | k(+256) | v(+512)].
// Block = 256 threads = 256 queries of one (b,h); grid (B, H, MAXW/256).
// ---------------------------------------------------------------------------
__global__ __launch_bounds__(256) void attn_kernel(
    const float* __restrict__ qkv, const int* __restrict__ lens,
    float* __restrict__ ct)
{
  const int b  = blockIdx.x;
  const int h  = blockIdx.y;
  const int qt = blockIdx.z;
  const int L  = lens[b];
  if (qt * 256 >= L) return;  // uniform early-exit, no barriers crossed

  int off = 0;
#pragma unroll
  for (int i = 0; i < 8; ++i) off += (i < b) ? lens[i] : 0;

  __shared__ float Ks[KT][HD];
  __shared__ float Vs[KT][HD];

  const int q = qt * 256 + threadIdx.x;
  const bool vq = (q < L);
  const float* qp = qkv + (size_t)(off + (vq ? q : 0)) * QKV_N + h * HD;
  float qreg[HD];
#pragma unroll
  for (int i = 0; i < HD / 4; ++i)
    *(float4*)&qreg[i * 4] = *(const float4*)(qp + i * 4);

  float m = -1e30f, l = 0.f;
  float acc[HD];
#pragma unroll
  for (int d = 0; d < HD; ++d) acc[d] = 0.f;

  // staging indices: 32 rows x 32 floats = 256 float4 -> one per thread
  const int srow = threadIdx.x >> 3;        // 0..31
  const int scc  = (threadIdx.x & 7) * 4;   // 0..28

  for (int k0 = 0; k0 < L; k0 += KT) {
    __syncthreads();  // previous tile's reads done
    {
      float4 kv = make_float4(0.f, 0.f, 0.f, 0.f);
      float4 vv = make_float4(0.f, 0.f, 0.f, 0.f);
      if (k0 + srow < L) {
        const float* p = qkv + (size_t)(off + k0 + srow) * QKV_N + h * HD + scc;
        kv = *(const float4*)(p + 256);
        vv = *(const float4*)(p + 512);
      }
      *(float4*)&Ks[srow][scc] = kv;
      *(float4*)&Vs[srow][scc] = vv;
    }
    __syncthreads();

    const int nv = min(KT, L - k0);
    float s[KT];
    float tmax = -1e30f;
#pragma unroll
    for (int j = 0; j < KT; ++j) {
      float d = 0.f;
#pragma unroll
      for (int dd = 0; dd < HD; dd += 4) {
        const float4 k4 = *(const float4*)&Ks[j][dd];
        d = fmaf(qreg[dd + 0], k4.x, d);
        d = fmaf(qreg[dd + 1], k4.y, d);
        d = fmaf(qreg[dd + 2], k4.z, d);
        d = fmaf(qreg[dd + 3], k4.w, d);
      }
      s[j] = (j < nv) ? d : -1e30f;
      tmax = fmaxf(tmax, s[j]);
    }

    const float nm = fmaxf(m, tmax);
    const float f = __expf(m - nm);
    l *= f;
#pragma unroll
    for (int d2 = 0; d2 < HD; ++d2) acc[d2] *= f;

#pragma unroll
    for (int j = 0; j < KT; ++j) {
      const float p = __expf(s[j] - nm);
      l += p;
#pragma unroll
      for (int dd = 0; dd < HD; dd += 4) {
        const float4 v4 = *(const float4*)&Vs[j][dd];
        acc[dd + 0] = fmaf(p, v4.x, acc[dd + 0]);
        acc[dd + 1] = fmaf(p, v4.y, acc[dd + 1]);
        acc[dd + 2] = fmaf(p, v4.z, acc[dd + 2]);
        acc[dd + 3] = fmaf(p, v4.w, acc[dd + 3]);
      }
    }
    m = nm;
  }

  if (vq) {
    const float inv = 1.f / l;
    float* op = ct + (size_t)(off + q) * C_DIM + h * HD;
#pragma unroll
    for (int i = 0; i < HD / 4; ++i) {
      float4 o;
      o.x = acc[i * 4 + 0] * inv;
      o.y = acc[i * 4 + 1] * inv;
      o.z = acc[i * 4 + 2] * inv;
      o.w = acc[i * 4 + 3] * inv;
      *(float4*)(op + i * 4) = o;
    }
  }
}

// ---------------------------------------------------------------------------
extern "C" void kernel_launch(void* const* d_in, const int* in_sizes, int n_in,
                              void* d_out, int out_size, void* d_ws, size_t ws_size,
                              hipStream_t stream) {
  const float* x      = (const float*)d_in[0];
  // d_in[1] = ct_mask : derivable from lens, never read
  const int*   lens   = (const int*)d_in[2];
  const float* qkv_w  = (const float*)d_in[3];
  const float* qkv_b  = (const float*)d_in[4];
  const float* proj_w = (const float*)d_in[5];
  const float* proj_b = (const float*)d_in[6];
  float* out = (float*)d_out;

  const int M = out_size / C_DIM;  // TOTAL tokens (6464)

  float* qkv = (float*)d_ws;                    // [M, 768]
  float* ct  = qkv + (size_t)M * QKV_N;         // [M, 256]

  const dim3 blk(256);

  // QKV projection (+bias, q-scale folded into cols < 256)
  dim3 g1((M + 63) / 64, QKV_N / 64);
  hipLaunchKernelGGL(gemm_bias_kernel, g1, blk, 0, stream,
                     x, qkv_w, qkv_b, qkv, M, QKV_N, 0.17677669529663687f, 256);

  // ragged attention
  dim3 g2(8, NH, 1024 / 256);
  hipLaunchKernelGGL(attn_kernel, g2, blk, 0, stream, qkv, lens, ct);

  // output projection
  dim3 g3((M + 63) / 64, C_DIM / 64);
  hipLaunchKernelGGL(gemm_bias_kernel, g3, blk, 0, stream,
                     ct, proj_w, proj_b, out, M, C_DIM, 1.f, 0);
}

// Round 2
// 230.130 us; speedup vs baseline: 1.9414x; 1.9414x over previous
//
#include <hip/hip_runtime.h>
#include <hip/hip_bf16.h>
#include <cstdint>

#define C_DIM 256
#define NH 8
#define HD 32
#define QKV_N 768

#define QB 32       // queries per block
#define KTILE 64    // keys per LDS tile
#define LDST 36     // LDS row stride in floats (bank-spread for 8 splits)

// ---------------------------------------------------------------------------
// Tiled fp32 GEMM: out[M,N] = A[M,256] @ W[256,N] + bias[N], with optional
// scale applied to columns < scale_cols (folds the q * hd^-0.5 scale).
// ---------------------------------------------------------------------------
__global__ __launch_bounds__(256) void gemm_bias_kernel(
    const float* __restrict__ A, const float* __restrict__ W,
    const float* __restrict__ bias, float* __restrict__ out,
    int M, int N, float scale, int scale_cols)
{
  __shared__ float As[16][72];
  __shared__ float Bs[16][64];
  const int K = 256;

  const int tid = threadIdx.x;
  const int tx = tid & 15, ty = tid >> 4;
  const int m0 = blockIdx.x * 64;
  const int n0 = blockIdx.y * 64;

  float acc[4][4];
#pragma unroll
  for (int i = 0; i < 4; ++i)
#pragma unroll
    for (int j = 0; j < 4; ++j) acc[i][j] = 0.f;

  const int lrow = tid >> 2;
  const int lc4  = (tid & 3) * 4;
  const int brow = tid >> 4;
  const int bc4  = (tid & 15) * 4;

  for (int k0 = 0; k0 < K; k0 += 16) {
    float4 av = make_float4(0.f, 0.f, 0.f, 0.f);
    const int gr = m0 + lrow;
    if (gr < M) av = *(const float4*)(A + (size_t)gr * K + k0 + lc4);
    const float4 bv = *(const float4*)(W + (size_t)(k0 + brow) * N + n0 + bc4);

    __syncthreads();
    As[lc4 + 0][lrow] = av.x;
    As[lc4 + 1][lrow] = av.y;
    As[lc4 + 2][lrow] = av.z;
    As[lc4 + 3][lrow] = av.w;
    *(float4*)&Bs[brow][bc4] = bv;
    __syncthreads();

#pragma unroll
    for (int kk = 0; kk < 16; ++kk) {
      float a[4], bb[4];
      *(float4*)a  = *(const float4*)&As[kk][ty * 4];
      *(float4*)bb = *(const float4*)&Bs[kk][tx * 4];
#pragma unroll
      for (int i = 0; i < 4; ++i)
#pragma unroll
        for (int j = 0; j < 4; ++j)
          acc[i][j] = fmaf(a[i], bb[j], acc[i][j]);
    }
  }

  const int col = n0 + tx * 4;
  const float4 bb = *(const float4*)(bias + col);
  const float sc = (col < scale_cols) ? scale : 1.f;
#pragma unroll
  for (int i = 0; i < 4; ++i) {
    const int r = m0 + ty * 4 + i;
    if (r < M) {
      float4 o;
      o.x = (acc[i][0] + bb.x) * sc;
      o.y = (acc[i][1] + bb.y) * sc;
      o.z = (acc[i][2] + bb.z) * sc;
      o.w = (acc[i][3] + bb.w) * sc;
      *(float4*)(out + (size_t)r * N + col) = o;
    }
  }
}

// ---------------------------------------------------------------------------
// Ragged attention with 8-way K-split per query.
// Block = 256 threads = 32 queries x 8 splits (splits contiguous in lane).
// Split s handles keys s, s+8, s+16, ... ; partial (m,l,acc) combined via
// __shfl_xor butterfly over the 8-lane group at the end.
// ---------------------------------------------------------------------------
__global__ __launch_bounds__(256) void attn_kernel(
    const float* __restrict__ qkv, const int* __restrict__ lens,
    float* __restrict__ ct)
{
  const int b  = blockIdx.x;
  const int h  = blockIdx.y;
  const int qt = blockIdx.z;
  const int L  = lens[b];
  if (qt * QB >= L) return;  // uniform early-exit before any barrier

  int off = 0;
#pragma unroll
  for (int i = 0; i < 8; ++i) off += (i < b) ? lens[i] : 0;

  __shared__ float Ks[KTILE][LDST];
  __shared__ float Vs[KTILE][LDST];

  const int tid = threadIdx.x;
  const int ql  = tid >> 3;   // 0..31 query within block
  const int sp  = tid & 7;    // 0..7  k-split
  const int q   = qt * QB + ql;
  const bool vq = (q < L);

  const float* qp = qkv + (size_t)(off + (vq ? q : 0)) * QKV_N + h * HD;
  float qreg[HD];
#pragma unroll
  for (int i = 0; i < HD / 4; ++i)
    *(float4*)&qreg[i * 4] = *(const float4*)(qp + i * 4);

  float m = -1e30f, l = 0.f;
  float acc[HD];
#pragma unroll
  for (int d = 0; d < HD; ++d) acc[d] = 0.f;

  // staging: KTILE rows x 32 floats (8 float4/row) for K and V.
  // 512 float4 each; thread handles element e = tid and tid+256.
  for (int k0 = 0; k0 < L; k0 += KTILE) {
    __syncthreads();  // previous tile's reads done
#pragma unroll
    for (int e0 = 0; e0 < 2; ++e0) {
      const int e   = tid + e0 * 256;
      const int row = e >> 3;
      const int c4  = (e & 7) * 4;
      float4 kv = make_float4(0.f, 0.f, 0.f, 0.f);
      float4 vv = make_float4(0.f, 0.f, 0.f, 0.f);
      if (k0 + row < L) {
        const float* p = qkv + (size_t)(off + k0 + row) * QKV_N + h * HD + c4;
        kv = *(const float4*)(p + 256);
        vv = *(const float4*)(p + 512);
      }
      *(float4*)&Ks[row][c4] = kv;
      *(float4*)&Vs[row][c4] = vv;
    }
    __syncthreads();

    float s[8];
    float tmax = -1e30f;
#pragma unroll
    for (int j = 0; j < 8; ++j) {
      const int r = sp + 8 * j;
      float d = 0.f;
#pragma unroll
      for (int dd = 0; dd < HD; dd += 4) {
        const float4 k4 = *(const float4*)&Ks[r][dd];
        d = fmaf(qreg[dd + 0], k4.x, d);
        d = fmaf(qreg[dd + 1], k4.y, d);
        d = fmaf(qreg[dd + 2], k4.z, d);
        d = fmaf(qreg[dd + 3], k4.w, d);
      }
      s[j] = (k0 + r < L) ? d : -1e30f;
      tmax = fmaxf(tmax, s[j]);
    }

    const float nm = fmaxf(m, tmax);
    const float f = __expf(m - nm);
    l *= f;
#pragma unroll
    for (int d2 = 0; d2 < HD; ++d2) acc[d2] *= f;

#pragma unroll
    for (int j = 0; j < 8; ++j) {
      const int r = sp + 8 * j;
      const float p = __expf(s[j] - nm);
      l += p;
#pragma unroll
      for (int dd = 0; dd < HD; dd += 4) {
        const float4 v4 = *(const float4*)&Vs[r][dd];
        acc[dd + 0] = fmaf(p, v4.x, acc[dd + 0]);
        acc[dd + 1] = fmaf(p, v4.y, acc[dd + 1]);
        acc[dd + 2] = fmaf(p, v4.z, acc[dd + 2]);
        acc[dd + 3] = fmaf(p, v4.w, acc[dd + 3]);
      }
    }
    m = nm;
  }

  // combine the 8 splits of each query (lanes q*8 .. q*8+7) via xor butterfly
#pragma unroll
  for (int w = 1; w < 8; w <<= 1) {
    const float mo = __shfl_xor(m, w, 64);
    const float lo = __shfl_xor(l, w, 64);
    const float nm = fmaxf(m, mo);
    const float fs = __expf(m - nm);
    const float fo = __expf(mo - nm);
    l = l * fs + lo * fo;
#pragma unroll
    for (int d = 0; d < HD; ++d) {
      const float ao = __shfl_xor(acc[d], w, 64);
      acc[d] = acc[d] * fs + ao * fo;
    }
    m = nm;
  }

  if (vq) {
    const float inv = 1.f / l;
    float* op = ct + (size_t)(off + q) * C_DIM + h * HD;
    // static-indexed predicated writes: lane sp writes chunk sp (rule #20)
#pragma unroll
    for (int d4 = 0; d4 < 8; ++d4) {
      if (d4 == sp) {
        float4 o;
        o.x = acc[d4 * 4 + 0] * inv;
        o.y = acc[d4 * 4 + 1] * inv;
        o.z = acc[d4 * 4 + 2] * inv;
        o.w = acc[d4 * 4 + 3] * inv;
        *(float4*)(op + d4 * 4) = o;
      }
    }
  }
}

// ---------------------------------------------------------------------------
extern "C" void kernel_launch(void* const* d_in, const int* in_sizes, int n_in,
                              void* d_out, int out_size, void* d_ws, size_t ws_size,
                              hipStream_t stream) {
  const float* x      = (const float*)d_in[0];
  // d_in[1] = ct_mask : derivable from lens, never read
  const int*   lens   = (const int*)d_in[2];
  const float* qkv_w  = (const float*)d_in[3];
  const float* qkv_b  = (const float*)d_in[4];
  const float* proj_w = (const float*)d_in[5];
  const float* proj_b = (const float*)d_in[6];
  float* out = (float*)d_out;

  const int M = out_size / C_DIM;  // TOTAL tokens (6464)

  float* qkv = (float*)d_ws;                 // [M, 768]
  float* ct  = qkv + (size_t)M * QKV_N;      // [M, 256]

  const dim3 blk(256);

  dim3 g1((M + 63) / 64, QKV_N / 64);
  hipLaunchKernelGGL(gemm_bias_kernel, g1, blk, 0, stream,
                     x, qkv_w, qkv_b, qkv, M, QKV_N, 0.17677669529663687f, 256);

  dim3 g2(8, NH, 1024 / QB);
  hipLaunchKernelGGL(attn_kernel, g2, blk, 0, stream, qkv, lens, ct);

  dim3 g3((M + 63) / 64, C_DIM / 64);
  hipLaunchKernelGGL(gemm_bias_kernel, g3, blk, 0, stream,
                     ct, proj_w, proj_b, out, M, C_DIM, 1.f, 0);
}

// Round 5
// 107.189 us; speedup vs baseline: 4.1680x; 2.1470x over previous
//
#include <hip/hip_runtime.h>
#include <hip/hip_bf16.h>
#include <cstdint>

#define C_DIM 256
#define NH 8
#define HD 32
#define QKV_N 768

typedef __attribute__((ext_vector_type(8))) short bf16x8;
typedef __attribute__((ext_vector_type(4))) float f32x4;

__device__ __forceinline__ unsigned short f2bf(float f) {
  union { float f; unsigned int u; } cv; cv.f = f;
  unsigned int u = cv.u + 0x7fffu + ((cv.u >> 16) & 1u);  // RNE
  return (unsigned short)(u >> 16);
}

// ---------------------------------------------------------------------------
// Tiled fp32 GEMM: out = A[M,256] @ W[256,N] + bias, scale on cols<scale_cols.
// Writes fp32 (out_f32) and/or bf16 (out_bf) — pass nullptr to skip either.
// ---------------------------------------------------------------------------
__global__ __launch_bounds__(256) void gemm_bias_kernel(
    const float* __restrict__ A, const float* __restrict__ W,
    const float* __restrict__ bias, float* __restrict__ out_f32,
    unsigned short* __restrict__ out_bf,
    int M, int N, float scale, int scale_cols)
{
  __shared__ float As[16][72];
  __shared__ float Bs[16][64];
  const int K = 256;

  const int tid = threadIdx.x;
  const int tx = tid & 15, ty = tid >> 4;
  const int m0 = blockIdx.x * 64;
  const int n0 = blockIdx.y * 64;

  float acc[4][4];
#pragma unroll
  for (int i = 0; i < 4; ++i)
#pragma unroll
    for (int j = 0; j < 4; ++j) acc[i][j] = 0.f;

  const int lrow = tid >> 2;
  const int lc4  = (tid & 3) * 4;
  const int brow = tid >> 4;
  const int bc4  = (tid & 15) * 4;

  for (int k0 = 0; k0 < K; k0 += 16) {
    float4 av = make_float4(0.f, 0.f, 0.f, 0.f);
    const int gr = m0 + lrow;
    if (gr < M) av = *(const float4*)(A + (size_t)gr * K + k0 + lc4);
    const float4 bv = *(const float4*)(W + (size_t)(k0 + brow) * N + n0 + bc4);

    __syncthreads();
    As[lc4 + 0][lrow] = av.x;
    As[lc4 + 1][lrow] = av.y;
    As[lc4 + 2][lrow] = av.z;
    As[lc4 + 3][lrow] = av.w;
    *(float4*)&Bs[brow][bc4] = bv;
    __syncthreads();

#pragma unroll
    for (int kk = 0; kk < 16; ++kk) {
      float a[4], bb[4];
      *(float4*)a  = *(const float4*)&As[kk][ty * 4];
      *(float4*)bb = *(const float4*)&Bs[kk][tx * 4];
#pragma unroll
      for (int i = 0; i < 4; ++i)
#pragma unroll
        for (int j = 0; j < 4; ++j)
          acc[i][j] = fmaf(a[i], bb[j], acc[i][j]);
    }
  }

  const int col = n0 + tx * 4;
  const float4 bb = *(const float4*)(bias + col);
  const float sc = (col < scale_cols) ? scale : 1.f;
#pragma unroll
  for (int i = 0; i < 4; ++i) {
    const int r = m0 + ty * 4 + i;
    if (r < M) {
      float4 o;
      o.x = (acc[i][0] + bb.x) * sc;
      o.y = (acc[i][1] + bb.y) * sc;
      o.z = (acc[i][2] + bb.z) * sc;
      o.w = (acc[i][3] + bb.w) * sc;
      if (out_f32) *(float4*)(out_f32 + (size_t)r * N + col) = o;
      if (out_bf) {
        ushort4 ob;
        ob.x = f2bf(o.x); ob.y = f2bf(o.y); ob.z = f2bf(o.z); ob.w = f2bf(o.w);
        *(ushort4*)(out_bf + (size_t)r * N + col) = ob;
      }
    }
  }
}

// ---------------------------------------------------------------------------
// MFMA flash attention over ragged batches.
// Block = 256 thr = 4 waves; each wave owns 16 queries; K/V tiles of 64 keys
// staged in LDS per block. Swapped QK^T: S^T = mfma(A=K, B=Q) so each lane
// holds scores for query q = lane&15 (stats lane-local after 2 shuffles).
// P packed bf16 -> per-wave LDS tile -> PV A-frags. V staged transposed so
// PV B-frags are contiguous ds_read_b128.
// ---------------------------------------------------------------------------
__global__ __launch_bounds__(256) void attn_mfma_kernel(
    const unsigned short* __restrict__ qkvb, const int* __restrict__ lens,
    float* __restrict__ ct)
{
  const int b = blockIdx.x, h = blockIdx.y, zt = blockIdx.z;
  const int L = lens[b];
  if (zt * 64 >= L) return;  // uniform exit before any barrier
  int off = 0;
#pragma unroll
  for (int i = 0; i < 8; ++i) off += (i < b) ? lens[i] : 0;

  __shared__ unsigned short Ks[64][40];    // [key][d], +8 pad
  __shared__ unsigned short Vt[32][72];    // [d][key], +8 pad (transposed)
  __shared__ unsigned short Pl[4][16][72]; // per-wave [q][key] bf16 P tile

  const int tid  = threadIdx.x;
  const int wid  = tid >> 6;
  const int lane = tid & 63;
  const int lq   = lane & 15;   // query (col) / frag row
  const int g    = lane >> 4;   // lane group 0..3

  const int qbase = zt * 64 + wid * 16;
  int qrow = qbase + lq; if (qrow >= L) qrow = L - 1;  // clamp; stores predicated
  // NOTE: ragged layout — Q row lives at off + qrow (this offset was the R2/R3 bug)
  const bf16x8 qf =
      *(const bf16x8*)(qkvb + (size_t)(off + qrow) * QKV_N + 32 * h + 8 * g);

  f32x4 acc0 = {0.f, 0.f, 0.f, 0.f};  // O[q=4g+r][d=lq]
  f32x4 acc1 = {0.f, 0.f, 0.f, 0.f};  // O[q=4g+r][d=lq+16]
  float m = -1e30f, lsum = 0.f;

  const int nt = (L + 63) >> 6;
  const int srow = tid >> 2, sch = tid & 3;

  for (int t = 0; t < nt; ++t) {
    const int k0 = t << 6;
    __syncthreads();  // previous tile fully consumed
    {
      uint4 kv = make_uint4(0, 0, 0, 0), vv = make_uint4(0, 0, 0, 0);
      if (k0 + srow < L) {
        const unsigned short* p =
            qkvb + (size_t)(off + k0 + srow) * QKV_N + 32 * h + 8 * sch;
        kv = *(const uint4*)(p + 256);
        vv = *(const uint4*)(p + 512);
      }
      *(uint4*)&Ks[srow][8 * sch] = kv;
      const unsigned short* vs = (const unsigned short*)&vv;
#pragma unroll
      for (int j = 0; j < 8; ++j) Vt[8 * sch + j][srow] = vs[j];
    }
    __syncthreads();

    // --- QK^T (swapped): s[c][r] = S[q=lq][k = k0 + 16c + 4g + r]
    const f32x4 zz = {0.f, 0.f, 0.f, 0.f};
    f32x4 s[4];
#pragma unroll
    for (int c = 0; c < 4; ++c) {
      const bf16x8 kf = *(const bf16x8*)&Ks[16 * c + lq][8 * g];
      s[c] = __builtin_amdgcn_mfma_f32_16x16x32_bf16(kf, qf, zz, 0, 0, 0);
    }

    if (k0 + 64 > L) {  // tail-tile key mask
#pragma unroll
      for (int c = 0; c < 4; ++c)
#pragma unroll
        for (int r = 0; r < 4; ++r)
          if (k0 + 16 * c + 4 * g + r >= L) s[c][r] = -1e30f;
    }

    // --- online softmax (per query lq, reduce over lane groups)
    float tmax = -1e30f;
#pragma unroll
    for (int c = 0; c < 4; ++c)
#pragma unroll
      for (int r = 0; r < 4; ++r) tmax = fmaxf(tmax, s[c][r]);
    tmax = fmaxf(tmax, __shfl_xor(tmax, 16, 64));
    tmax = fmaxf(tmax, __shfl_xor(tmax, 32, 64));

    const float nm  = fmaxf(m, tmax);
    const float fsc = __expf(m - nm);
    m = nm;

    float p[4][4];
    float ls = 0.f;
#pragma unroll
    for (int c = 0; c < 4; ++c)
#pragma unroll
      for (int r = 0; r < 4; ++r) {
        p[c][r] = __expf(s[c][r] - nm);
        ls += p[c][r];
      }
    ls += __shfl_xor(ls, 16, 64);
    ls += __shfl_xor(ls, 32, 64);
    lsum = lsum * fsc + ls;

    // rescale O rows (q = 4g+r); stats live at lane q (uniform across groups)
#pragma unroll
    for (int r = 0; r < 4; ++r) {
      const float fr = __shfl(fsc, 4 * g + r, 64);
      acc0[r] *= fr;
      acc1[r] *= fr;
    }

    // --- P (fp32 regs) -> bf16 pairs -> per-wave LDS tile
#pragma unroll
    for (int c = 0; c < 4; ++c)
#pragma unroll
      for (int rr = 0; rr < 2; ++rr) {
        const unsigned int pkt =
            (unsigned int)f2bf(p[c][2 * rr]) |
            ((unsigned int)f2bf(p[c][2 * rr + 1]) << 16);
        *(unsigned int*)&Pl[wid][lq][16 * c + 4 * g + 2 * rr] = pkt;
      }
    // COMPILER FENCE: P tile written as uint, read as short-vector (TBAA
    // no-alias) — keep stores and the dependent ds_reads ordered. HW DS is
    // in-order per-wave, so a compiler-level fence suffices.
    asm volatile("" ::: "memory");

    // --- PV: O += P[16,64] @ V[64,32]
#pragma unroll
    for (int mm = 0; mm < 2; ++mm) {
      const bf16x8 pa = *(const bf16x8*)&Pl[wid][lq][32 * mm + 8 * g];
      const bf16x8 v0 = *(const bf16x8*)&Vt[lq][32 * mm + 8 * g];
      const bf16x8 v1 = *(const bf16x8*)&Vt[lq + 16][32 * mm + 8 * g];
      acc0 = __builtin_amdgcn_mfma_f32_16x16x32_bf16(pa, v0, acc0, 0, 0, 0);
      acc1 = __builtin_amdgcn_mfma_f32_16x16x32_bf16(pa, v1, acc1, 0, 0, 0);
    }
  }

  // --- normalize + store (O row q = 4g+r, cols d = lq, lq+16)
  const float linv = 1.f / lsum;
#pragma unroll
  for (int r = 0; r < 4; ++r) {
    const float lr = __shfl(linv, 4 * g + r, 64);
    const int q = qbase + 4 * g + r;
    if (q < L) {
      float* op = ct + (size_t)(off + q) * C_DIM + 32 * h;
      op[lq]      = acc0[r] * lr;
      op[lq + 16] = acc1[r] * lr;
    }
  }
}

// ---------------------------------------------------------------------------
extern "C" void kernel_launch(void* const* d_in, const int* in_sizes, int n_in,
                              void* d_out, int out_size, void* d_ws, size_t ws_size,
                              hipStream_t stream) {
  const float* x      = (const float*)d_in[0];
  // d_in[1] = ct_mask : derivable from lens, never read
  const int*   lens   = (const int*)d_in[2];
  const float* qkv_w  = (const float*)d_in[3];
  const float* qkv_b  = (const float*)d_in[4];
  const float* proj_w = (const float*)d_in[5];
  const float* proj_b = (const float*)d_in[6];
  float* out = (float*)d_out;

  const int M = out_size / C_DIM;  // TOTAL tokens (6464)

  unsigned short* qkv_bf = (unsigned short*)d_ws;              // [M, 768] bf16
  float* ct = (float*)((char*)d_ws + (size_t)M * QKV_N * 2);   // [M, 256] f32

  const dim3 blk(256);

  // QKV projection -> bf16 (q-scale folded into cols < 256)
  dim3 g1((M + 63) / 64, QKV_N / 64);
  hipLaunchKernelGGL(gemm_bias_kernel, g1, blk, 0, stream,
                     x, qkv_w, qkv_b, (float*)nullptr, qkv_bf,
                     M, QKV_N, 0.17677669529663687f, 256);

  // MFMA flash attention
  dim3 g2(8, NH, 1024 / 64);
  hipLaunchKernelGGL(attn_mfma_kernel, g2, blk, 0, stream, qkv_bf, lens, ct);

  // output projection (fp32)
  dim3 g3((M + 63) / 64, C_DIM / 64);
  hipLaunchKernelGGL(gemm_bias_kernel, g3, blk, 0, stream,
                     ct, proj_w, proj_b, out, (unsigned short*)nullptr,
                     M, C_DIM, 1.f, 0);
}